// Round 4
// baseline (234.952 us; speedup 1.0000x reference)
//
#include <hip/hip_runtime.h>

// NonSpikingInput: RK2 leaky integrator; per step v' = A*v + B*i with
// A = 0.625, B = 0.075 (E_REST = I_BIAS = 0). Output = (4096, 8192) fp32
// history. Memory-bound: ~268 MB -> ~43 us floor at 6.3 TB/s.
//
// R3 -> R4: LDS/barrier version was latency-limited (occ 33%, 2.5 TB/s).
// Replace with a barrier-free wave-level weighted-prefix scan:
//  - lane loads float4 (timesteps 4*lane..4*lane+3 of a 256-step window),
//    folds them to a linear map v_out = w*v_in + c, w = A^4 (exact fp32).
//  - weighted Kogge-Stone over lanes: S_i = sum_j w^(i-j) c_j. Since
//    w^16 = A^64 ~ 8.6e-14, offsets {1,2,4,8} suffice (64-step history,
//    same truncation bound validated in R1/R3, threshold 1.1e-2).
//  - carry across iterations = shfl(S,63); across half-row waves = one
//    redundant warm-up iteration (no store).
// No LDS, no __syncthreads, ~40 VGPR -> 32 waves/CU; loads are independent
// of the carry chain and prefetched one iteration ahead.

typedef float fx4 __attribute__((ext_vector_type(4)));

constexpr int TT  = 8192;   // time steps per row
constexpr int BLK = 256;    // 4 waves/block; each wave owns half a row

__global__ __launch_bounds__(BLK, 8)
void neuron_scan(const float* __restrict__ in, float* __restrict__ out) {
    const float A = 0.625f;
    const float B = 0.075f;
    const float w1 = 0.152587890625f;   // A^4  (exact in fp32)
    const float w2 = w1 * w1;           // A^8
    const float w4 = w2 * w2;           // A^16
    const float w8 = w4 * w4;           // A^32

    const int lane = threadIdx.x & 63;
    const int wid  = blockIdx.x * (BLK / 64) + (threadIdx.x >> 6);
    const int row  = wid >> 1;
    const int half = wid & 1;

    // w^lane for carry injection (underflows to 0 past lane ~28 -- harmless).
    float wl = 1.0f;
    {
        float p = w1;
        int lb = lane;
        #pragma unroll
        for (int b = 0; b < 6; ++b) {
            if (lb & 1) wl *= p;
            p *= p;
            lb >>= 1;
        }
    }

    const size_t base_off = (size_t)row * TT + (size_t)half * (TT / 2);
    const float* base = in + base_off;
    float* obase = out + base_off;

    float carry = 0.0f;
    int it = half ? -1 : 0;             // -1 = warm-up iteration (no store)
    fx4 x = *(const fx4*)(base + it * 256 + (lane << 2));

    while (it < 16) {
        const fx4 xc = x;
        const int itn = it + 1;
        if (itn < 16)                   // wave-uniform; prefetch next window
            x = *(const fx4*)(base + itn * 256 + (lane << 2));

        // Fold own 4 steps: segment constant c (v_out = w1*v_in + c).
        const float c0 = B * xc.x;
        const float c1 = fmaf(A, c0, B * xc.y);
        const float c2 = fmaf(A, c1, B * xc.z);
        const float c3 = fmaf(A, c2, B * xc.w);

        // Weighted Kogge-Stone inclusive scan (truncated at 16 lanes back).
        float S = c3, t;
        t = __shfl_up(S, 1); S = (lane >= 1) ? fmaf(w1, t, S) : S;
        t = __shfl_up(S, 2); S = (lane >= 2) ? fmaf(w2, t, S) : S;
        t = __shfl_up(S, 4); S = (lane >= 4) ? fmaf(w4, t, S) : S;
        t = __shfl_up(S, 8); S = (lane >= 8) ? fmaf(w8, t, S) : S;

        // Exclusive value + carry injection -> v entering this lane's segment.
        float E = __shfl_up(S, 1);
        E = (lane >= 1) ? E : 0.0f;
        const float vin = fmaf(wl, carry, E);
        carry = __shfl(S, 63);          // v at end of this 256-step window

        if (it >= 0) {                  // wave-uniform (skip store on warm-up)
            fx4 o;
            o.x = fmaf(A, vin, B * xc.x);
            o.y = fmaf(A, o.x, B * xc.y);
            o.z = fmaf(A, o.y, B * xc.z);
            o.w = fmaf(A, o.z, B * xc.w);
            __builtin_nontemporal_store(o, (fx4*)(obase + it * 256 + (lane << 2)));
        }
        it = itn;
    }
}

extern "C" void kernel_launch(void* const* d_in, const int* in_sizes, int n_in,
                              void* d_out, int out_size, void* d_ws, size_t ws_size,
                              hipStream_t stream) {
    const float* in = (const float*)d_in[0];
    float* out = (float*)d_out;
    const int n_rows = in_sizes[0] / TT;          // 4096
    const int n_blocks = n_rows / 2;              // 2 waves/row, 4 waves/block
    neuron_scan<<<dim3(n_blocks), dim3(BLK), 0, stream>>>(in, out);
}